// Round 9
// baseline (315.291 us; speedup 1.0000x reference)
//
#include <hip/hip_runtime.h>
#include <hip/hip_bf16.h>

#define E_EDGES 393216
#define NRECV   12288
#define DX      128
#define BATCH   2

typedef short bf16x8 __attribute__((ext_vector_type(8)));
typedef float f32x4  __attribute__((ext_vector_type(4)));

__device__ __forceinline__ unsigned short f2bf(float f) {
  union { float f; unsigned u; } v; v.f = f;
  unsigned r = v.u + 0x7FFFu + ((v.u >> 16) & 1u);  // RNE
  return (unsigned short)(r >> 16);
}

__device__ __forceinline__ unsigned pk2(float a, float b) {
  __hip_bfloat162 h = __float22bfloat162_rn(make_float2(a, b));
  union { __hip_bfloat162 h; unsigned u; } c; c.h = h;
  return c.u;
}

__device__ __forceinline__ float silu_f(float v) {
  float e = __builtin_amdgcn_exp2f(v * -1.44269504089f);
  return v * __builtin_amdgcn_rcpf(1.0f + e);
}

// fast zero fill: n float4s, grid-stride
__global__ __launch_bounds__(256) void zero_kernel(float4* __restrict__ p, int n4) {
  int i = blockIdx.x * 256 + threadIdx.x;
  int stride = gridDim.x * 256;
  float4 z = make_float4(0.f, 0.f, 0.f, 0.f);
  for (; i < n4; i += stride) p[i] = z;
}

// All weight pre-swizzles in one launch.
__global__ __launch_bounds__(256) void swz_all_kernel(
    const float* __restrict__ w1e, const float* __restrict__ b1e,
    const float* __restrict__ w2e, const float* __restrict__ w1f,
    const float* __restrict__ w2f,
    unsigned short* __restrict__ w1sw, unsigned short* __restrict__ w2esw,
    unsigned short* __restrict__ w1fsw, unsigned short* __restrict__ w2fsw) {
  int blk = blockIdx.x;
  if (blk < 160) {
    int t = blk * 256 + threadIdx.x;  // 0..40959
    int j = t & 7, l = (t >> 3) & 63, rest = t >> 9;
    int nf = rest & 15, ks = rest >> 4;
    int k = ks * 32 + (l >> 4) * 8 + j;
    int n = nf * 16 + (l & 15);
    float v = (k < 132) ? w1e[k * 256 + n] : (k == 132 ? b1e[n] : 0.0f);
    w1sw[t] = f2bf(v);
  } else {
    int g = blk - 160;
    int which = g >> 8;
    int t = (g & 255) * 256 + threadIdx.x;  // 0..65535
    const float* W = (which == 0) ? w2e : (which == 1) ? w1f : w2f;
    unsigned short* O = (which == 0) ? w2esw : (which == 1) ? w1fsw : w2fsw;
    int j = t & 7, l = (t >> 3) & 63, rest = t >> 9;
    int nf = rest & 15, ks = rest >> 4;
    int k = ks * 32 + (l >> 4) * 8 + j;
    int n = nf * 16 + (l & 15);
    O[t] = f2bf(W[k * 256 + n]);
  }
}

__global__ void hist_kernel(const int* __restrict__ recv, int* __restrict__ cnt) {
  int e = blockIdx.x * 256 + threadIdx.x;
  if (e < E_EDGES) atomicAdd(&cnt[recv[e]], 1);
}

// exclusive prefix of cnt[12288] -> head[12288]; single block of 256
__global__ __launch_bounds__(256) void scan_kernel(const int* __restrict__ cnt,
                                                   int* __restrict__ head) {
  __shared__ int ts[256];
  const int t = threadIdx.x;
  const int base = t * 48;
  int s = 0;
#pragma unroll
  for (int i = 0; i < 48; ++i) s += cnt[base + i];
  ts[t] = s;
  __syncthreads();
  for (int d = 1; d < 256; d <<= 1) {
    int v = (t >= d) ? ts[t - d] : 0;
    __syncthreads();
    ts[t] += v;
    __syncthreads();
  }
  int run = (t == 0) ? 0 : ts[t - 1];
  for (int i = 0; i < 48; ++i) { head[base + i] = run; run += cnt[base + i]; }
}

__global__ void scatter_kernel(const int* __restrict__ recv, int* __restrict__ head,
                               int* __restrict__ perm) {
  int e = blockIdx.x * 256 + threadIdx.x;
  if (e < E_EDGES) {
    int pos = atomicAdd(&head[recv[e]], 1);
    perm[pos] = e;
  }
}

// silu + pack + cross-lane shuffle into seg-MFMA B-frags; acc is DEAD afterward.
__device__ __forceinline__ void build_hbw(const f32x4 (&acc)[4][4],
                                          unsigned (&hbw)[2][4][4], int lo, int hi) {
  // dest lane (hi,lo) dword t4 of frag (kk,nf) = h[e=kk*32+hi*8+2*t4..+1][c=w*64+nf*16+lo]
#pragma unroll
  for (int kk = 0; kk < 2; ++kk)
#pragma unroll
    for (int nf = 0; nf < 4; ++nf) {
      unsigned pA[2], pB[2];
      pA[0] = pk2(silu_f(acc[2 * kk][nf][0]), silu_f(acc[2 * kk][nf][1]));
      pA[1] = pk2(silu_f(acc[2 * kk][nf][2]), silu_f(acc[2 * kk][nf][3]));
      pB[0] = pk2(silu_f(acc[2 * kk + 1][nf][0]), silu_f(acc[2 * kk + 1][nf][1]));
      pB[1] = pk2(silu_f(acc[2 * kk + 1][nf][2]), silu_f(acc[2 * kk + 1][nf][3]));
#pragma unroll
      for (int t4 = 0; t4 < 4; ++t4) {
        int src = ((hi & 1) * 2 + (t4 >> 1)) * 16 + lo;
        int a0 = __shfl((int)pA[t4 & 1], src, 64);
        int a1 = __shfl((int)pB[t4 & 1], src, 64);
        hbw[kk][nf][t4] = (hi & 2) ? (unsigned)a1 : (unsigned)a0;
      }
    }
}

// indicator MFMA segmented sum + atomic scatter; 16 segments per pass.
__device__ __forceinline__ void seg_scatter(
    const unsigned (&hbw)[2][4][4], float* __restrict__ sb,
    const unsigned* __restrict__ seg32, const int* __restrict__ seg_recv,
    int nseg, int lo, int hi, int w) {
  for (int p = 0; p * 16 < nseg; ++p) {
    union { unsigned u[4]; bf16x8 v; } ia[2];
#pragma unroll
    for (int kk = 0; kk < 2; ++kk) {
      unsigned d0 = seg32[kk * 8 + hi * 2];
      unsigned d1 = seg32[kk * 8 + hi * 2 + 1];
      unsigned tgt = (unsigned)(lo + p * 16);
      ia[kk].u[0] = (((d0 & 255u) == tgt) ? 0x3F80u : 0u) |
                    ((((d0 >> 8) & 255u) == tgt) ? 0x3F800000u : 0u);
      ia[kk].u[1] = ((((d0 >> 16) & 255u) == tgt) ? 0x3F80u : 0u) |
                    (((d0 >> 24) == tgt) ? 0x3F800000u : 0u);
      ia[kk].u[2] = (((d1 & 255u) == tgt) ? 0x3F80u : 0u) |
                    ((((d1 >> 8) & 255u) == tgt) ? 0x3F800000u : 0u);
      ia[kk].u[3] = ((((d1 >> 16) & 255u) == tgt) ? 0x3F80u : 0u) |
                    (((d1 >> 24) == tgt) ? 0x3F800000u : 0u);
    }
    f32x4 accS[4] = {};
#pragma unroll
    for (int kk = 0; kk < 2; ++kk)
#pragma unroll
      for (int nf = 0; nf < 4; ++nf) {
        union { unsigned u[4]; bf16x8 v; } hb;
        hb.u[0] = hbw[kk][nf][0]; hb.u[1] = hbw[kk][nf][1];
        hb.u[2] = hbw[kk][nf][2]; hb.u[3] = hbw[kk][nf][3];
        accS[nf] = __builtin_amdgcn_mfma_f32_16x16x32_bf16(ia[kk].v, hb.v, accS[nf], 0, 0, 0);
      }
#pragma unroll
    for (int j = 0; j < 4; ++j) {
      int sidx = p * 16 + hi * 4 + j;
      if (sidx < nseg) {
        int rcv = seg_recv[sidx];
#pragma unroll
        for (int nf = 0; nf < 4; ++nf)
          atomicAdd(sb + (size_t)rcv * 256 + w * 64 + nf * 16 + lo, accS[nf][j]);
      }
    }
  }
}

// Edge layer-1 over receiver-sorted edges; BOTH batches per block.
// K padded to 160: cols 0..3 = edge_attr, 4..131 = x, 132 = 1.0 (bias), rest 0.
// Batch-1 gather issues AFTER acc dies (hbw0 built) -> reuses acc's registers,
// latency hides under batch-0's indicator-MFMA + atomic scatter.
__global__ __launch_bounds__(256, 4) void edge_kernel(
    const float* __restrict__ x, const float* __restrict__ edge_attr,
    const int* __restrict__ recv, const int* __restrict__ perm,
    const unsigned short* __restrict__ w1sw, float* __restrict__ s) {
  __shared__ __align__(16) char As[64 * 384];  // 24576 B
  __shared__ int rs[64];
  __shared__ int seg_recv[64];
  __shared__ unsigned seg32[16];               // u8 seg id per row

  const int tid = threadIdx.x;
  const int l  = tid & 63;
  const int w  = tid >> 6;
  const int lo = l & 15, hi = l >> 4;
  const int p0 = blockIdx.x * 64;
  const int r = tid >> 2, q = tid & 3;
  const int rx = (r & 7) << 4;
  const int axor = (lo & 7) << 4;

  // ---- issue batch-0 gather FIRST ----
  const int er = perm[p0 + r];
  const float4* xr0 = (const float4*)(x + (size_t)er * DX);
  float4 xv[8];
#pragma unroll
  for (int i = 0; i < 8; ++i) xv[i] = xr0[i * 4 + q];  // i*4+q: whole 64B lines

  float4 ea = make_float4(0, 0, 0, 0);
  int rsv = 0;
  if (tid < 64) {
    int e1 = perm[p0 + tid];
    rsv = recv[e1];
    ea = *(const float4*)(edge_attr + (size_t)e1 * 4);
  }

  // pad cols 132..191 once (col 132 = 1.0bf bias input, rest 0); no integer div
  {
    const int rr = tid & 63;
    const int rxr = (rr & 7) << 4;
#pragma unroll
    for (int k2 = tid >> 6; k2 < 15; k2 += 4) {
      int byte0 = 264 + 8 * k2;
      uint2 vz = make_uint2(k2 == 0 ? 0x00003F80u : 0u, 0u);
      *(uint2*)(As + rr * 384 + (byte0 ^ rxr)) = vz;
    }
  }

  // write batch-0 x + ea -> swizzled bf16 As; rs
#pragma unroll
  for (int i = 0; i < 8; ++i) {
    int t_ = i * 4 + q;
    int byte0 = 8 + 8 * t_;
    *(uint2*)(As + r * 384 + (byte0 ^ rx)) =
        make_uint2(pk2(xv[i].x, xv[i].y), pk2(xv[i].z, xv[i].w));
  }
  if (tid < 64) {
    *(uint2*)(As + tid * 384 + ((tid & 7) << 4)) =
        make_uint2(pk2(ea.x, ea.y), pk2(ea.z, ea.w));
    rs[tid] = rsv;
  }
  __syncthreads();  // bar1: As/rs visible

  // ---- segment metadata (shared by both batches) ----
  const int flag = (l == 63) || (rs[l + 1] != rs[l]);
  const unsigned long long segmask = __ballot(flag);
  const int nseg = __popcll(segmask);
  if (tid < 64) {
    int sid = __popcll(segmask & ((1ull << tid) - 1ull));
    ((unsigned char*)seg32)[tid] = (unsigned char)sid;
    if (flag) seg_recv[sid] = rsv;
  }

  // ---- MFMA batch 0 ----
  f32x4 acc[4][4] = {};
#pragma unroll
  for (int kk = 0; kk < 5; ++kk) {
    bf16x8 a[4];
#pragma unroll
    for (int mf = 0; mf < 4; ++mf)
      a[mf] = *(const bf16x8*)(As + (mf * 16 + lo) * 384 + ((kk * 64 + hi * 16) ^ axor));
#pragma unroll
    for (int nf = 0; nf < 4; ++nf) {
      bf16x8 bb = *(const bf16x8*)&w1sw[(size_t)(((kk * 16) + (w * 4 + nf)) * 64 + l) * 8];
#pragma unroll
      for (int mf = 0; mf < 4; ++mf)
        acc[mf][nf] = __builtin_amdgcn_mfma_f32_16x16x32_bf16(a[mf], bb, acc[mf][nf], 0, 0, 0);
    }
  }
  __syncthreads();  // bar2: As reads done; seg32/seg_recv visible

  // ---- extract hbw0: acc registers die here ----
  unsigned hbw[2][4][4];
  build_hbw(acc, hbw, lo, hi);

  // ---- NOW issue batch-1 gather (reuses acc's register space) ----
  const float4* xr1 = (const float4*)(x + ((size_t)E_EDGES + er) * DX);
  float4 y[8];
#pragma unroll
  for (int i = 0; i < 8; ++i) y[i] = xr1[i * 4 + q];

  // ---- batch-0 segmented scatter (hides y latency) ----
  seg_scatter(hbw, s, seg32, seg_recv, nseg, lo, hi, w);

  // ---- rewrite only the x bytes of As for batch 1 (ea/pad/bias unchanged) ----
#pragma unroll
  for (int i = 0; i < 8; ++i) {
    int t_ = i * 4 + q;
    int byte0 = 8 + 8 * t_;
    *(uint2*)(As + r * 384 + (byte0 ^ rx)) =
        make_uint2(pk2(y[i].x, y[i].y), pk2(y[i].z, y[i].w));
  }
  __syncthreads();  // bar3: batch-1 As visible

  // ---- MFMA batch 1 ----
#pragma unroll
  for (int mf = 0; mf < 4; ++mf)
#pragma unroll
    for (int nf = 0; nf < 4; ++nf) acc[mf][nf] = (f32x4){0.f, 0.f, 0.f, 0.f};
#pragma unroll
  for (int kk = 0; kk < 5; ++kk) {
    bf16x8 a[4];
#pragma unroll
    for (int mf = 0; mf < 4; ++mf)
      a[mf] = *(const bf16x8*)(As + (mf * 16 + lo) * 384 + ((kk * 64 + hi * 16) ^ axor));
#pragma unroll
    for (int nf = 0; nf < 4; ++nf) {
      bf16x8 bb = *(const bf16x8*)&w1sw[(size_t)(((kk * 16) + (w * 4 + nf)) * 64 + l) * 8];
#pragma unroll
      for (int mf = 0; mf < 4; ++mf)
        acc[mf][nf] = __builtin_amdgcn_mfma_f32_16x16x32_bf16(a[mf], bb, acc[mf][nf], 0, 0, 0);
    }
  }

  // ---- batch-1 extract + segmented scatter ----
  build_hbw(acc, hbw, lo, hi);
  seg_scatter(hbw, s + (size_t)NRECV * 256, seg32, seg_recv, nseg, lo, hi, w);
}

__device__ __forceinline__ void gemm64(const unsigned short* Ns,
                                       const unsigned short* __restrict__ Bsw,
                                       int w, int l, f32x4 acc[4][4]) {
  const int lo = l & 15, hi = l >> 4;
#pragma unroll
  for (int kk = 0; kk < 8; ++kk) {
    bf16x8 a[4], bb[4];
#pragma unroll
    for (int mf = 0; mf < 4; ++mf)
      a[mf] = *(const bf16x8*)&Ns[(mf * 16 + lo) * 264 + kk * 32 + hi * 8];
#pragma unroll
    for (int nf = 0; nf < 4; ++nf)
      bb[nf] = *(const bf16x8*)&Bsw[(size_t)(((kk * 16) + (w * 4 + nf)) * 64 + l) * 8];
#pragma unroll
    for (int mf = 0; mf < 4; ++mf)
#pragma unroll
      for (int nf = 0; nf < 4; ++nf)
        acc[mf][nf] = __builtin_amdgcn_mfma_f32_16x16x32_bf16(a[mf], bb[nf], acc[mf][nf], 0, 0, 0);
  }
}

// Node pass: vm = s@w2e + cnt*b2e; out = silu(vm@w1f + b1f)@w2f + b2f
__global__ __launch_bounds__(256) void node_kernel(
    const float* __restrict__ s, const int* __restrict__ cnt,
    const unsigned short* __restrict__ w2esw, const float* __restrict__ b2e,
    const unsigned short* __restrict__ w1fsw, const float* __restrict__ b1f,
    const unsigned short* __restrict__ w2fsw, const float* __restrict__ b2f,
    float* __restrict__ out) {
  __shared__ unsigned short Ns[64 * 264];
  __shared__ int   cntl[64];
  __shared__ float bias1[256], bias2[256], bias3[256];

  const int tid = threadIdx.x;
  const int l  = tid & 63;
  const int w  = tid >> 6;
  const int lo = l & 15, hi = l >> 4;
  const int r0 = blockIdx.x * 64;
  const int b  = blockIdx.y;

  const float4* sb = (const float4*)(s + ((size_t)b * NRECV + r0) * 256);
#pragma unroll
  for (int i = 0; i < 16; ++i) {
    int f = i * 256 + tid;
    float4 v = sb[f];
    int g = f * 4;
    int row = g >> 8, col = g & 255;
    *(uint2*)&Ns[row * 264 + col] = make_uint2(pk2(v.x, v.y), pk2(v.z, v.w));
  }
  if (tid < 64) cntl[tid] = cnt[r0 + tid];
  bias1[tid] = b2e[tid];
  bias2[tid] = b1f[tid];
  bias3[tid] = b2f[tid];
  __syncthreads();

  {
    f32x4 acc[4][4] = {};
    gemm64(Ns, w2esw, w, l, acc);
    __syncthreads();
#pragma unroll
    for (int mf = 0; mf < 4; ++mf)
#pragma unroll
      for (int nf = 0; nf < 4; ++nf) {
        const int col = w * 64 + nf * 16 + lo;
#pragma unroll
        for (int j = 0; j < 4; ++j) {
          const int row = mf * 16 + hi * 4 + j;
          float v = acc[mf][nf][j] + (float)cntl[row] * bias1[col];
          Ns[row * 264 + col] = f2bf(v);
        }
      }
    __syncthreads();
  }
  {
    f32x4 acc[4][4] = {};
    gemm64(Ns, w1fsw, w, l, acc);
    __syncthreads();
#pragma unroll
    for (int mf = 0; mf < 4; ++mf)
#pragma unroll
      for (int nf = 0; nf < 4; ++nf) {
        const int col = w * 64 + nf * 16 + lo;
#pragma unroll
        for (int j = 0; j < 4; ++j) {
          const int row = mf * 16 + hi * 4 + j;
          float v = silu_f(acc[mf][nf][j] + bias2[col]);
          Ns[row * 264 + col] = f2bf(v);
        }
      }
    __syncthreads();
  }
  {
    f32x4 acc[4][4] = {};
    gemm64(Ns, w2fsw, w, l, acc);
#pragma unroll
    for (int mf = 0; mf < 4; ++mf)
#pragma unroll
      for (int nf = 0; nf < 4; ++nf) {
        const int col = w * 64 + nf * 16 + lo;
#pragma unroll
        for (int j = 0; j < 4; ++j) {
          const int row = mf * 16 + hi * 4 + j;
          out[((size_t)b * NRECV + r0 + row) * 256 + col] = acc[mf][nf][j] + bias3[col];
        }
      }
  }
}

extern "C" void kernel_launch(void* const* d_in, const int* in_sizes, int n_in,
                              void* d_out, int out_size, void* d_ws, size_t ws_size,
                              hipStream_t stream) {
  const float* x         = (const float*)d_in[0];
  const float* edge_attr = (const float*)d_in[1];
  const int*   edge_idx  = (const int*)d_in[2];
  const float* w1e       = (const float*)d_in[3];
  const float* b1e       = (const float*)d_in[4];
  const float* w2e       = (const float*)d_in[5];
  const float* b2e       = (const float*)d_in[6];
  const float* w1f       = (const float*)d_in[7];
  const float* b1f       = (const float*)d_in[8];
  const float* w2f       = (const float*)d_in[9];
  const float* b2f       = (const float*)d_in[10];
  float* out = (float*)d_out;

  char* ws = (char*)d_ws;
  float*          sbuf  = (float*)(ws + 0);                    // 25165824
  int*            cnt   = (int*)(ws + 25165824);               // 49152
  int*            head  = (int*)(ws + 25214976);               // 49152
  int*            perm  = (int*)(ws + 25264128);               // 1572864
  unsigned short* w1sw  = (unsigned short*)(ws + 26836992);    // 160*256*2 = 81920
  unsigned short* w2esw = (unsigned short*)(ws + 26918912);    // 131072
  unsigned short* w1fsw = (unsigned short*)(ws + 27049984);    // 131072
  unsigned short* w2fsw = (unsigned short*)(ws + 27181056);    // 131072

  // zero s + cnt (25214976 B = 1575936 float4s)
  zero_kernel<<<2048, 256, 0, stream>>>((float4*)ws, 1575936);

  swz_all_kernel<<<928, 256, 0, stream>>>(w1e, b1e, w2e, w1f, w2f,
                                          w1sw, w2esw, w1fsw, w2fsw);

  const int* recv = edge_idx + E_EDGES;  // edge_index[1]
  hist_kernel<<<E_EDGES / 256, 256, 0, stream>>>(recv, cnt);
  scan_kernel<<<1, 256, 0, stream>>>(cnt, head);
  scatter_kernel<<<E_EDGES / 256, 256, 0, stream>>>(recv, head, perm);

  edge_kernel<<<E_EDGES / 64, 256, 0, stream>>>(x, edge_attr, recv, perm, w1sw, sbuf);

  dim3 ng(NRECV / 64, BATCH);
  node_kernel<<<ng, 256, 0, stream>>>(sbuf, cnt, w2esw, b2e, w1fsw, b1f, w2fsw, b2f, out);
}

// Round 10
// 241.114 us; speedup vs baseline: 1.3076x; 1.3076x over previous
//
#include <hip/hip_runtime.h>
#include <hip/hip_bf16.h>

#define E_EDGES 393216
#define NRECV   12288
#define DX      128
#define BATCH   2

typedef short bf16x8 __attribute__((ext_vector_type(8)));
typedef float f32x4  __attribute__((ext_vector_type(4)));

__device__ __forceinline__ unsigned short f2bf(float f) {
  union { float f; unsigned u; } v; v.f = f;
  unsigned r = v.u + 0x7FFFu + ((v.u >> 16) & 1u);  // RNE
  return (unsigned short)(r >> 16);
}

__device__ __forceinline__ unsigned pk2(float a, float b) {
  __hip_bfloat162 h = __float22bfloat162_rn(make_float2(a, b));
  union { __hip_bfloat162 h; unsigned u; } c; c.h = h;
  return c.u;
}

__device__ __forceinline__ float silu_f(float v) {
  float e = __builtin_amdgcn_exp2f(v * -1.44269504089f);
  return v * __builtin_amdgcn_rcpf(1.0f + e);
}

// fast zero fill: n float4s, grid-stride
__global__ __launch_bounds__(256) void zero_kernel(float4* __restrict__ p, int n4) {
  int i = blockIdx.x * 256 + threadIdx.x;
  int stride = gridDim.x * 256;
  float4 z = make_float4(0.f, 0.f, 0.f, 0.f);
  for (; i < n4; i += stride) p[i] = z;
}

// All weight pre-swizzles in one launch.
__global__ __launch_bounds__(256) void swz_all_kernel(
    const float* __restrict__ w1e, const float* __restrict__ b1e,
    const float* __restrict__ w2e, const float* __restrict__ w1f,
    const float* __restrict__ w2f,
    unsigned short* __restrict__ w1sw, unsigned short* __restrict__ w2esw,
    unsigned short* __restrict__ w1fsw, unsigned short* __restrict__ w2fsw) {
  int blk = blockIdx.x;
  if (blk < 160) {
    int t = blk * 256 + threadIdx.x;  // 0..40959
    int j = t & 7, l = (t >> 3) & 63, rest = t >> 9;
    int nf = rest & 15, ks = rest >> 4;
    int k = ks * 32 + (l >> 4) * 8 + j;
    int n = nf * 16 + (l & 15);
    float v = (k < 132) ? w1e[k * 256 + n] : (k == 132 ? b1e[n] : 0.0f);
    w1sw[t] = f2bf(v);
  } else {
    int g = blk - 160;
    int which = g >> 8;
    int t = (g & 255) * 256 + threadIdx.x;  // 0..65535
    const float* W = (which == 0) ? w2e : (which == 1) ? w1f : w2f;
    unsigned short* O = (which == 0) ? w2esw : (which == 1) ? w1fsw : w2fsw;
    int j = t & 7, l = (t >> 3) & 63, rest = t >> 9;
    int nf = rest & 15, ks = rest >> 4;
    int k = ks * 32 + (l >> 4) * 8 + j;
    int n = nf * 16 + (l & 15);
    O[t] = f2bf(W[k * 256 + n]);
  }
}

__global__ void hist_kernel(const int* __restrict__ recv, int* __restrict__ cnt) {
  int e = blockIdx.x * 256 + threadIdx.x;
  if (e < E_EDGES) atomicAdd(&cnt[recv[e]], 1);
}

// exclusive prefix of cnt[12288] -> head[12288]; single block of 256
__global__ __launch_bounds__(256) void scan_kernel(const int* __restrict__ cnt,
                                                   int* __restrict__ head) {
  __shared__ int ts[256];
  const int t = threadIdx.x;
  const int base = t * 48;
  int s = 0;
#pragma unroll
  for (int i = 0; i < 48; ++i) s += cnt[base + i];
  ts[t] = s;
  __syncthreads();
  for (int d = 1; d < 256; d <<= 1) {
    int v = (t >= d) ? ts[t - d] : 0;
    __syncthreads();
    ts[t] += v;
    __syncthreads();
  }
  int run = (t == 0) ? 0 : ts[t - 1];
  for (int i = 0; i < 48; ++i) { head[base + i] = run; run += cnt[base + i]; }
}

__global__ void scatter_kernel(const int* __restrict__ recv, int* __restrict__ head,
                               int* __restrict__ perm) {
  int e = blockIdx.x * 256 + threadIdx.x;
  if (e < E_EDGES) {
    int pos = atomicAdd(&head[recv[e]], 1);
    perm[pos] = e;
  }
}

// Edge layer-1 over receiver-sorted edges. K padded to 160: cols 0..3 = edge_attr,
// 4..131 = x, 132 = 1.0 (bias row folded into w1sw), 133..159 = 0.
// As XOR-swizzled (byte ^= (row&7)<<4 in 128B windows).
// h never leaves registers: seg-sum B-frags built by cross-lane shuffles (INLINE,
// straight-line — device-fn array refs spilled to scratch in r7/r9).
// w1sw B-frags software-pipelined one kk ahead (cur/nxt rotation).
__global__ __launch_bounds__(256, 4) void edge_kernel(
    const float* __restrict__ x, const float* __restrict__ edge_attr,
    const int* __restrict__ recv, const int* __restrict__ perm,
    const unsigned short* __restrict__ w1sw, float* __restrict__ s) {
  __shared__ __align__(16) char As[64 * 384];  // 24576 B
  __shared__ int rs[64];
  __shared__ int seg_recv[64];
  __shared__ unsigned seg32[16];               // u8 seg id per row

  const int tid = threadIdx.x;
  const int l  = tid & 63;
  const int w  = tid >> 6;
  const int lo = l & 15, hi = l >> 4;
  const int p0 = blockIdx.x * 64;
  const int b  = blockIdx.y;

  // ---- issue gather loads FIRST (no LDS dependency) ----
  const int r = tid >> 2, q = tid & 3;
  const int er = perm[p0 + r];
  const float4* xr = (const float4*)(x + ((size_t)b * E_EDGES + er) * DX);
  float4 xv[8];
#pragma unroll
  for (int i = 0; i < 8; ++i) xv[i] = xr[i * 4 + q];  // i*4+q: whole 64B lines per instr

  float4 ea;
  if (tid < 64) {
    int e1 = perm[p0 + tid];
    rs[tid] = recv[e1];
    ea = *(const float4*)(edge_attr + (size_t)e1 * 4);
  }

  // pad cols 132..191: col 132 = 1.0bf (bias input), rest 0; swizzled
  for (int idx = tid; idx < 960; idx += 256) {
    int rr = idx / 15, k2 = idx - rr * 15;
    int byte0 = 264 + 8 * k2;
    uint2 vz = make_uint2(k2 == 0 ? 0x00003F80u : 0u, 0u);
    *(uint2*)(As + rr * 384 + (byte0 ^ ((rr & 7) << 4))) = vz;
  }

  // write gathered x -> swizzled bf16 As
  {
    const int rx = (r & 7) << 4;
#pragma unroll
    for (int i = 0; i < 8; ++i) {
      int t = i * 4 + q;
      int byte0 = 8 + 8 * t;
      *(uint2*)(As + r * 384 + (byte0 ^ rx)) =
          make_uint2(pk2(xv[i].x, xv[i].y), pk2(xv[i].z, xv[i].w));
    }
  }
  if (tid < 64) {
    *(uint2*)(As + tid * 384 + ((tid & 7) << 4)) =
        make_uint2(pk2(ea.x, ea.y), pk2(ea.z, ea.w));
  }
  __syncthreads();

  // segment metadata: per-wave ballot (identical across waves); wave0 publishes ids
  const int flag = (l == 63) || (rs[l + 1] != rs[l]);
  const unsigned long long segmask = __ballot(flag);
  const int nseg = __popcll(segmask);
  if (tid < 64) {
    int sid = __popcll(segmask & ((1ull << tid) - 1ull));
    ((unsigned char*)seg32)[tid] = (unsigned char)sid;
    if (flag) seg_recv[sid] = rs[tid];
  }

  // ---- main MFMA: h = silu-input tile, acc[mf][nf] rows=edges cols=hidden ----
  // B-frag (kk,nf) at w1sw elem ((kk*16 + w*4 + nf)*64 + l)*8; pipeline cur/nxt.
  f32x4 acc[4][4] = {};
  const int axor = (lo & 7) << 4;  // A-row & 7 == lo & 7 since rows are mf*16+lo
  const unsigned short* wbase = w1sw + ((size_t)(w * 4) * 64 + l) * 8;
  bf16x8 cur0 = *(const bf16x8*)(wbase + 0 * 512);
  bf16x8 cur1 = *(const bf16x8*)(wbase + 1 * 512);
  bf16x8 cur2 = *(const bf16x8*)(wbase + 2 * 512);
  bf16x8 cur3 = *(const bf16x8*)(wbase + 3 * 512);
#pragma unroll
  for (int kk = 0; kk < 5; ++kk) {
    bf16x8 a[4];
#pragma unroll
    for (int mf = 0; mf < 4; ++mf)
      a[mf] = *(const bf16x8*)(As + (mf * 16 + lo) * 384 + ((kk * 64 + hi * 16) ^ axor));
    bf16x8 nxt0, nxt1, nxt2, nxt3;
    if (kk < 4) {
      const unsigned short* wn = wbase + (size_t)(kk + 1) * 8192;
      nxt0 = *(const bf16x8*)(wn + 0 * 512);
      nxt1 = *(const bf16x8*)(wn + 1 * 512);
      nxt2 = *(const bf16x8*)(wn + 2 * 512);
      nxt3 = *(const bf16x8*)(wn + 3 * 512);
    }
    __builtin_amdgcn_s_setprio(1);
#pragma unroll
    for (int mf = 0; mf < 4; ++mf)
      acc[mf][0] = __builtin_amdgcn_mfma_f32_16x16x32_bf16(a[mf], cur0, acc[mf][0], 0, 0, 0);
#pragma unroll
    for (int mf = 0; mf < 4; ++mf)
      acc[mf][1] = __builtin_amdgcn_mfma_f32_16x16x32_bf16(a[mf], cur1, acc[mf][1], 0, 0, 0);
#pragma unroll
    for (int mf = 0; mf < 4; ++mf)
      acc[mf][2] = __builtin_amdgcn_mfma_f32_16x16x32_bf16(a[mf], cur2, acc[mf][2], 0, 0, 0);
#pragma unroll
    for (int mf = 0; mf < 4; ++mf)
      acc[mf][3] = __builtin_amdgcn_mfma_f32_16x16x32_bf16(a[mf], cur3, acc[mf][3], 0, 0, 0);
    __builtin_amdgcn_s_setprio(0);
    if (kk < 4) { cur0 = nxt0; cur1 = nxt1; cur2 = nxt2; cur3 = nxt3; }
  }
  __syncthreads();  // seg32/seg_recv visible to all waves

  // ---- silu + pack to bf16 pairs (row pairs (0,1),(2,3) per fragment) ----
  unsigned pkd[4][4][2];
#pragma unroll
  for (int mf = 0; mf < 4; ++mf)
#pragma unroll
    for (int nf = 0; nf < 4; ++nf) {
      float v0 = silu_f(acc[mf][nf][0]);
      float v1 = silu_f(acc[mf][nf][1]);
      float v2 = silu_f(acc[mf][nf][2]);
      float v3 = silu_f(acc[mf][nf][3]);
      pkd[mf][nf][0] = pk2(v0, v1);
      pkd[mf][nf][1] = pk2(v2, v3);
    }

  // ---- build segment-MFMA B-frags in-register via shuffles ----
  // dest lane (hi,lo) dword t of frag (kk,nf) = h[e=kk*32+hi*8+2t..+1][c=w*64+nf*16+lo]
  // src lane = ((hi&1)*2 + (t>>1))*16 + lo; mf = 2kk + (hi>>1); pair idx = t&1
  unsigned hbw[2][4][4];
#pragma unroll
  for (int kk = 0; kk < 2; ++kk)
#pragma unroll
    for (int nf = 0; nf < 4; ++nf)
#pragma unroll
      for (int t = 0; t < 4; ++t) {
        int src = ((hi & 1) * 2 + (t >> 1)) * 16 + lo;
        int a0 = __shfl((int)pkd[2 * kk][nf][t & 1], src, 64);
        int a1 = __shfl((int)pkd[2 * kk + 1][nf][t & 1], src, 64);
        hbw[kk][nf][t] = (hi & 2) ? (unsigned)a1 : (unsigned)a0;
      }

  // ---- segmented sum S = I^T @ h via indicator MFMA; 16 segs/pass ----
  float* sb = s + (size_t)b * NRECV * 256;
  for (int p = 0; p * 16 < nseg; ++p) {
    union { unsigned u[4]; bf16x8 v; } ia[2];
#pragma unroll
    for (int kk = 0; kk < 2; ++kk) {
      unsigned d0 = seg32[kk * 8 + hi * 2];
      unsigned d1 = seg32[kk * 8 + hi * 2 + 1];
      unsigned tgt = (unsigned)(lo + p * 16);
      ia[kk].u[0] = (((d0 & 255u) == tgt) ? 0x3F80u : 0u) |
                    ((((d0 >> 8) & 255u) == tgt) ? 0x3F800000u : 0u);
      ia[kk].u[1] = ((((d0 >> 16) & 255u) == tgt) ? 0x3F80u : 0u) |
                    (((d0 >> 24) == tgt) ? 0x3F800000u : 0u);
      ia[kk].u[2] = (((d1 & 255u) == tgt) ? 0x3F80u : 0u) |
                    ((((d1 >> 8) & 255u) == tgt) ? 0x3F800000u : 0u);
      ia[kk].u[3] = ((((d1 >> 16) & 255u) == tgt) ? 0x3F80u : 0u) |
                    (((d1 >> 24) == tgt) ? 0x3F800000u : 0u);
    }
    f32x4 accS[4] = {};
    __builtin_amdgcn_s_setprio(1);
#pragma unroll
    for (int kk = 0; kk < 2; ++kk)
#pragma unroll
      for (int nf = 0; nf < 4; ++nf) {
        union { unsigned u[4]; bf16x8 v; } hb;
        hb.u[0] = hbw[kk][nf][0]; hb.u[1] = hbw[kk][nf][1];
        hb.u[2] = hbw[kk][nf][2]; hb.u[3] = hbw[kk][nf][3];
        accS[nf] = __builtin_amdgcn_mfma_f32_16x16x32_bf16(ia[kk].v, hb.v, accS[nf], 0, 0, 0);
      }
    __builtin_amdgcn_s_setprio(0);
#pragma unroll
    for (int j = 0; j < 4; ++j) {
      int sidx = p * 16 + hi * 4 + j;
      if (sidx < nseg) {
        int rcv = seg_recv[sidx];
#pragma unroll
        for (int nf = 0; nf < 4; ++nf)
          atomicAdd(sb + (size_t)rcv * 256 + w * 64 + nf * 16 + lo, accS[nf][j]);
      }
    }
  }
}

__device__ __forceinline__ void gemm64(const unsigned short* Ns,
                                       const unsigned short* __restrict__ Bsw,
                                       int w, int l, f32x4 acc[4][4]) {
  const int lo = l & 15, hi = l >> 4;
#pragma unroll
  for (int kk = 0; kk < 8; ++kk) {
    bf16x8 a[4], bb[4];
#pragma unroll
    for (int mf = 0; mf < 4; ++mf)
      a[mf] = *(const bf16x8*)&Ns[(mf * 16 + lo) * 264 + kk * 32 + hi * 8];
#pragma unroll
    for (int nf = 0; nf < 4; ++nf)
      bb[nf] = *(const bf16x8*)&Bsw[(size_t)(((kk * 16) + (w * 4 + nf)) * 64 + l) * 8];
#pragma unroll
    for (int mf = 0; mf < 4; ++mf)
#pragma unroll
      for (int nf = 0; nf < 4; ++nf)
        acc[mf][nf] = __builtin_amdgcn_mfma_f32_16x16x32_bf16(a[mf], bb[nf], acc[mf][nf], 0, 0, 0);
  }
}

// Node pass: vm = s@w2e + cnt*b2e; out = silu(vm@w1f + b1f)@w2f + b2f
__global__ __launch_bounds__(256) void node_kernel(
    const float* __restrict__ s, const int* __restrict__ cnt,
    const unsigned short* __restrict__ w2esw, const float* __restrict__ b2e,
    const unsigned short* __restrict__ w1fsw, const float* __restrict__ b1f,
    const unsigned short* __restrict__ w2fsw, const float* __restrict__ b2f,
    float* __restrict__ out) {
  __shared__ unsigned short Ns[64 * 264];
  __shared__ int   cntl[64];
  __shared__ float bias1[256], bias2[256], bias3[256];

  const int tid = threadIdx.x;
  const int l  = tid & 63;
  const int w  = tid >> 6;
  const int lo = l & 15, hi = l >> 4;
  const int r0 = blockIdx.x * 64;
  const int b  = blockIdx.y;

  const float4* sb = (const float4*)(s + ((size_t)b * NRECV + r0) * 256);
#pragma unroll
  for (int i = 0; i < 16; ++i) {
    int f = i * 256 + tid;
    float4 v = sb[f];
    int g = f * 4;
    int row = g >> 8, col = g & 255;
    *(uint2*)&Ns[row * 264 + col] = make_uint2(pk2(v.x, v.y), pk2(v.z, v.w));
  }
  if (tid < 64) cntl[tid] = cnt[r0 + tid];
  bias1[tid] = b2e[tid];
  bias2[tid] = b1f[tid];
  bias3[tid] = b2f[tid];
  __syncthreads();

  {
    f32x4 acc[4][4] = {};
    gemm64(Ns, w2esw, w, l, acc);
    __syncthreads();
#pragma unroll
    for (int mf = 0; mf < 4; ++mf)
#pragma unroll
      for (int nf = 0; nf < 4; ++nf) {
        const int col = w * 64 + nf * 16 + lo;
#pragma unroll
        for (int j = 0; j < 4; ++j) {
          const int row = mf * 16 + hi * 4 + j;
          float v = acc[mf][nf][j] + (float)cntl[row] * bias1[col];
          Ns[row * 264 + col] = f2bf(v);
        }
      }
    __syncthreads();
  }
  {
    f32x4 acc[4][4] = {};
    gemm64(Ns, w1fsw, w, l, acc);
    __syncthreads();
#pragma unroll
    for (int mf = 0; mf < 4; ++mf)
#pragma unroll
      for (int nf = 0; nf < 4; ++nf) {
        const int col = w * 64 + nf * 16 + lo;
#pragma unroll
        for (int j = 0; j < 4; ++j) {
          const int row = mf * 16 + hi * 4 + j;
          float v = silu_f(acc[mf][nf][j] + bias2[col]);
          Ns[row * 264 + col] = f2bf(v);
        }
      }
    __syncthreads();
  }
  {
    f32x4 acc[4][4] = {};
    gemm64(Ns, w2fsw, w, l, acc);
#pragma unroll
    for (int mf = 0; mf < 4; ++mf)
#pragma unroll
      for (int nf = 0; nf < 4; ++nf) {
        const int col = w * 64 + nf * 16 + lo;
#pragma unroll
        for (int j = 0; j < 4; ++j) {
          const int row = mf * 16 + hi * 4 + j;
          out[((size_t)b * NRECV + r0 + row) * 256 + col] = acc[mf][nf][j] + bias3[col];
        }
      }
  }
}

extern "C" void kernel_launch(void* const* d_in, const int* in_sizes, int n_in,
                              void* d_out, int out_size, void* d_ws, size_t ws_size,
                              hipStream_t stream) {
  const float* x         = (const float*)d_in[0];
  const float* edge_attr = (const float*)d_in[1];
  const int*   edge_idx  = (const int*)d_in[2];
  const float* w1e       = (const float*)d_in[3];
  const float* b1e       = (const float*)d_in[4];
  const float* w2e       = (const float*)d_in[5];
  const float* b2e       = (const float*)d_in[6];
  const float* w1f       = (const float*)d_in[7];
  const float* b1f       = (const float*)d_in[8];
  const float* w2f       = (const float*)d_in[9];
  const float* b2f       = (const float*)d_in[10];
  float* out = (float*)d_out;

  char* ws = (char*)d_ws;
  float*          sbuf  = (float*)(ws + 0);                    // 25165824
  int*            cnt   = (int*)(ws + 25165824);               // 49152
  int*            head  = (int*)(ws + 25214976);               // 49152
  int*            perm  = (int*)(ws + 25264128);               // 1572864
  unsigned short* w1sw  = (unsigned short*)(ws + 26836992);    // 160*256*2 = 81920
  unsigned short* w2esw = (unsigned short*)(ws + 26918912);    // 131072
  unsigned short* w1fsw = (unsigned short*)(ws + 27049984);    // 131072
  unsigned short* w2fsw = (unsigned short*)(ws + 27181056);    // 131072

  // zero s + cnt (25214976 B = 1575936 float4s)
  zero_kernel<<<2048, 256, 0, stream>>>((float4*)ws, 1575936);

  swz_all_kernel<<<928, 256, 0, stream>>>(w1e, b1e, w2e, w1f, w2f,
                                          w1sw, w2esw, w1fsw, w2fsw);

  const int* recv = edge_idx + E_EDGES;  // edge_index[1]
  hist_kernel<<<E_EDGES / 256, 256, 0, stream>>>(recv, cnt);
  scan_kernel<<<1, 256, 0, stream>>>(cnt, head);
  scatter_kernel<<<E_EDGES / 256, 256, 0, stream>>>(recv, head, perm);

  dim3 eg(E_EDGES / 64, BATCH);
  edge_kernel<<<eg, 256, 0, stream>>>(x, edge_attr, recv, perm, w1sw, sbuf);

  dim3 ng(NRECV / 64, BATCH);
  node_kernel<<<ng, 256, 0, stream>>>(sbuf, cnt, w2esw, b2e, w1fsw, b1f, w2fsw, b2f, out);
}